// Round 13
// baseline (135.318 us; speedup 1.0000x reference)
//
#include <hip/hip_runtime.h>

#define B  16
#define S  4096
#define R  512          // LORA_RANK
#define QR 1536         // Q_LORA_RANK
#define H  32
#define D  128
#define HD 4096         // H*D
#define SC 64           // s-chunk per block (fp32 chunk fits LDS: 64x512x4 = 128 KB)
#define CH 64           // S/SC

using f32x4 = __attribute__((ext_vector_type(4))) float;
using s16x8 = __attribute__((ext_vector_type(8))) short;
union bfu { s16x8 v; uint u[4]; };

__device__ __forceinline__ ushort bf_hi(float x) {
  return (ushort)(__float_as_uint(x) >> 16);        // truncation
}
__device__ __forceinline__ float hi_f(float x) {
  return __uint_as_float(__float_as_uint(x) & 0xFFFF0000u);
}
__device__ __forceinline__ uint pack_hi2(float x, float y) {  // [bf16(x)|bf16(y)<<16]
  return (__float_as_uint(x) >> 16) | (__float_as_uint(y) & 0xFFFF0000u);
}
__device__ __forceinline__ ushort f2bf_rne(float x) {
  uint u = __float_as_uint(x);
  return (ushort)((u + 0x7FFFu + ((u >> 16) & 1u)) >> 16);
}
__device__ __forceinline__ float bf2f(ushort u) {
  return __uint_as_float((uint)u << 16);
}

// ---------------------------------------------------------------------------
// Kernel A: q[b,o] = hsq[b,:] . Wq[o,:] + bq[o]
// ---------------------------------------------------------------------------
__global__ __launch_bounds__(512) void k_q(const float* __restrict__ hsq,
                                           const float* __restrict__ Wq,
                                           const float* __restrict__ bq,
                                           float* __restrict__ q) {
  __shared__ float hs[B * QR];  // 96 KiB
  int tid = threadIdx.x;
  for (int idx = tid * 4; idx < B * QR; idx += 2048)
    *(float4*)&hs[idx] = *(const float4*)&hsq[idx];
  __syncthreads();

  int wave = tid >> 6, lane = tid & 63;
  int o = blockIdx.x * 16 + wave * 2;

  float acc0[B], acc1[B];
#pragma unroll
  for (int b = 0; b < B; ++b) { acc0[b] = 0.f; acc1[b] = 0.f; }

  const float* w0r = Wq + (size_t)o * QR;
  const float* w1r = w0r + QR;
  for (int k = lane * 4; k < QR; k += 256) {
    float4 wa = *(const float4*)&w0r[k];
    float4 wb = *(const float4*)&w1r[k];
#pragma unroll
    for (int b = 0; b < B; ++b) {
      float4 h4 = *(const float4*)&hs[b * QR + k];
      acc0[b] += wa.x * h4.x + wa.y * h4.y + wa.z * h4.z + wa.w * h4.w;
      acc1[b] += wb.x * h4.x + wb.y * h4.y + wb.z * h4.z + wb.w * h4.w;
    }
  }
#pragma unroll
  for (int b = 0; b < B; ++b) {
    float v0 = acc0[b], v1 = acc1[b];
#pragma unroll
    for (int off = 32; off > 0; off >>= 1) {
      v0 += __shfl_xor(v0, off);
      v1 += __shfl_xor(v1, off);
    }
    if (lane == 0) {
      q[b * HD + o]     = v0 + bq[o];
      q[b * HD + o + 1] = v1 + bq[o + 1];
    }
  }
}

// ---------------------------------------------------------------------------
// Kernel B: qhat = q . Wkv per head, emitted as bf16 hi/lo split (k-major).
// ---------------------------------------------------------------------------
__global__ __launch_bounds__(256) void k_qhat(const float* __restrict__ q,
                                              const float* __restrict__ Wkv,
                                              ushort* __restrict__ qhi,
                                              ushort* __restrict__ qlo) {
  int h = blockIdx.x;
  int r0 = blockIdx.y * 64;
  __shared__ float qs[B][D];
  int tid = threadIdx.x;
  for (int idx = tid; idx < B * D; idx += 256) {
    int b = idx >> 7, d = idx & (D - 1);
    qs[b][d] = q[b * HD + h * D + d];
  }
  __syncthreads();

  int r_l = tid & 63, bg = tid >> 6;
  float acc[4] = {0.f, 0.f, 0.f, 0.f};
  const float* wbase = Wkv + (size_t)(h * D) * R + r0 + r_l;
  for (int d = 0; d < D; d += 4) {
    float w0 = wbase[(d + 0) * R];
    float w1 = wbase[(d + 1) * R];
    float w2 = wbase[(d + 2) * R];
    float w3 = wbase[(d + 3) * R];
#pragma unroll
    for (int i = 0; i < 4; ++i) {
      float4 q4 = *(const float4*)&qs[bg * 4 + i][d];
      acc[i] += q4.x * w0 + q4.y * w1 + q4.z * w2 + q4.w * w3;
    }
  }
#pragma unroll
  for (int i = 0; i < 4; ++i) {
    size_t idx = ((size_t)(bg * 4 + i) * H + h) * R + r0 + r_l;
    qhi[idx] = bf_hi(acc[i]);
    qlo[idx] = bf_hi(acc[i] - hi_f(acc[i]));
  }
}

// ---------------------------------------------------------------------------
// Fused MFMA flash kernel v8 — SINGLE PASS over ckv.
// grid (B, CH=64) x 512 threads (8 waves), 1 blk/CU (133 KB LDS).
// Stage: whole [64 s][512 r] fp32 ckv chunk -> swizzled LDS (contiguous
//   global region, 16 float4/thread, one barrier).
// Phase 1 (no barriers): QK^T. A-frags: direct b128 loads of pre-split
//   qhi/qlo (L1/L2-hot). B-frags: fp32 LDS rows, hi/lo split in-reg,
//   3 MFMAs (hh + hl + lh) = fp32-grade logits.
// softmax: register + tiny cross-wave LDS reduce (2 barriers).
// Phase 2 (no barriers): PV. A-frags: transposed scalar reads FROM THE SAME
//   LDS TILE (zero extra global traffic); B-frags: P bf16 from swizzled Ps.
// Swizzle: 16-B block jb of row s stored at jb ^ ((s ^ (s>>3)) & 7).
// q.bkv logit term cancels in softmax.
// ---------------------------------------------------------------------------
__global__ __launch_bounds__(512, 2) void k_fmha(const ushort* __restrict__ qhi,
                                                 const ushort* __restrict__ qlo,
                                                 const float* __restrict__ ckv,
                                                 ushort* __restrict__ part,
                                                 float* __restrict__ mbuf,
                                                 float* __restrict__ lbuf) {
  __shared__ __align__(16) float  Vt[SC * R];     // 128 KB
  __shared__ __align__(16) ushort Ps[H * SC];     // 4 KB
  __shared__ float redm[H * 4];                   // 512 B
  __shared__ float redl[H * 4];                   // 512 B

  const int b = blockIdx.x, chunk = blockIdx.y;
  const int tid = threadIdx.x;
  const int lane = tid & 63, wv = tid >> 6;
  const int lcol = lane & 15, lgrp = lane >> 4;

  const float* cbase = ckv + ((size_t)b * S + (size_t)chunk * SC) * R;

  // ---------------- stage: one coalesced pass, swizzled ----------------
  {
    const int s = tid >> 3, cb = tid & 7;
    const float* src = cbase + (size_t)s * R + cb * 64;
    const int key = (s ^ (s >> 3)) & 7;
    float* drow = &Vt[s * R];
#pragma unroll
    for (int jj = 0; jj < 16; ++jj) {
      float4 v = *(const float4*)(src + 4 * jj);
      int jb = cb * 16 + jj;
      *(float4*)&drow[4 * (jb ^ key)] = v;
    }
  }
  __syncthreads();

  // ---------------- phase 1: QK^T (no barriers) ----------------
  const int mhalf = wv & 1, stile = wv >> 1;
  const ushort* qh_w = qhi + ((size_t)b * H + mhalf * 16 + lcol) * R;
  const ushort* ql_w = qlo + ((size_t)b * H + mhalf * 16 + lcol) * R;
  const int s_f = stile * 16 + lcol;
  const int keyf = (s_f ^ (s_f >> 3)) & 7;
  const float* frow = &Vt[s_f * R];

  f32x4 acc = {0.f, 0.f, 0.f, 0.f};
#pragma unroll
  for (int ks = 0; ks < 16; ++ks) {
    s16x8 ah = *(const s16x8*)&qh_w[ks * 32 + 8 * lgrp];
    s16x8 al = *(const s16x8*)&ql_w[ks * 32 + 8 * lgrp];
    const int jb0 = ks * 8 + 2 * lgrp;
    float4 fa = *(const float4*)&frow[4 * (jb0 ^ keyf)];
    float4 fb = *(const float4*)&frow[4 * ((jb0 + 1) ^ keyf)];
    bfu bh, bl;
    bh.u[0] = pack_hi2(fa.x, fa.y); bh.u[1] = pack_hi2(fa.z, fa.w);
    bh.u[2] = pack_hi2(fb.x, fb.y); bh.u[3] = pack_hi2(fb.z, fb.w);
    bl.u[0] = pack_hi2(fa.x - hi_f(fa.x), fa.y - hi_f(fa.y));
    bl.u[1] = pack_hi2(fa.z - hi_f(fa.z), fa.w - hi_f(fa.w));
    bl.u[2] = pack_hi2(fb.x - hi_f(fb.x), fb.y - hi_f(fb.y));
    bl.u[3] = pack_hi2(fb.z - hi_f(fb.z), fb.w - hi_f(fb.w));
    acc = __builtin_amdgcn_mfma_f32_16x16x32_bf16(ah, bh.v, acc, 0, 0, 0);
    acc = __builtin_amdgcn_mfma_f32_16x16x32_bf16(ah, bl.v, acc, 0, 0, 0);
    acc = __builtin_amdgcn_mfma_f32_16x16x32_bf16(al, bh.v, acc, 0, 0, 0);
  }

  // ---------------- softmax ----------------
  // D layout: h = mhalf*16 + 4*lgrp + i ; s = stile*16 + lcol
  {
    float m4[4];
#pragma unroll
    for (int i = 0; i < 4; ++i) m4[i] = acc[i];
#pragma unroll
    for (int off = 1; off <= 8; off <<= 1)
#pragma unroll
      for (int i = 0; i < 4; ++i) m4[i] = fmaxf(m4[i], __shfl_xor(m4[i], off));
    if (lcol == 0) {
#pragma unroll
      for (int i = 0; i < 4; ++i)
        redm[(mhalf * 16 + 4 * lgrp + i) * 4 + stile] = m4[i];
    }
  }
  __syncthreads();

  float e_[4], ps4[4];
#pragma unroll
  for (int i = 0; i < 4; ++i) {
    int h = mhalf * 16 + 4 * lgrp + i;
    float4 rm = *(float4*)&redm[h * 4];
    float m = fmaxf(fmaxf(rm.x, rm.y), fmaxf(rm.z, rm.w));
    e_[i] = __expf(acc[i] - m);
    ps4[i] = e_[i];
  }
#pragma unroll
  for (int off = 1; off <= 8; off <<= 1)
#pragma unroll
    for (int i = 0; i < 4; ++i) ps4[i] += __shfl_xor(ps4[i], off);
  if (lcol == 0) {
#pragma unroll
    for (int i = 0; i < 4; ++i)
      redl[(mhalf * 16 + 4 * lgrp + i) * 4 + stile] = ps4[i];
  }
  // P -> Ps (bf16, swizzled: block sb of row h at sb ^ (h&7))
#pragma unroll
  for (int i = 0; i < 4; ++i) {
    int h = mhalf * 16 + 4 * lgrp + i;
    int so = stile * 16 + lcol;
    Ps[h * 64 + 8 * (((so >> 3) ^ h) & 7) + (so & 7)] = f2bf_rne(e_[i]);
  }
  __syncthreads();

  if (wv < 2 && lcol == 0) {
#pragma unroll
    for (int i = 0; i < 4; ++i) {
      int h = wv * 16 + 4 * lgrp + i;
      float4 rm = *(float4*)&redm[h * 4];
      float M = fmaxf(fmaxf(rm.x, rm.y), fmaxf(rm.z, rm.w));
      float4 rl = *(float4*)&redl[h * 4];
      float L = rl.x + rl.y + rl.z + rl.w;
      mbuf[((size_t)b * CH + chunk) * H + h] = M;
      lbuf[((size_t)b * CH + chunk) * H + h] = L;
    }
  }

  // ---------------- phase 2: PV from the SAME LDS tile (no barriers) ------
  const int nt = wv & 1, rq = wv >> 1;
  const int hB = nt * 16 + lcol;
  s16x8 bp[2];
#pragma unroll
  for (int k2 = 0; k2 < 2; ++k2)
    bp[k2] = *(const s16x8*)&Ps[hB * 64 + 8 * (((4 * k2 + lgrp) ^ hB) & 7)];

  ushort* pb2 = part + (size_t)(b * CH + chunk) * H * R;
#pragma unroll
  for (int rt = 0; rt < 8; ++rt) {
    const int rtile = rq * 128 + rt * 16;
    const int r = rtile + lcol;
    const int jbr = r >> 2, re = r & 3;
    f32x4 a2 = {0.f, 0.f, 0.f, 0.f};
#pragma unroll
    for (int k2 = 0; k2 < 2; ++k2) {
      float f[8];
#pragma unroll
      for (int j = 0; j < 8; ++j) {
        int s = k2 * 32 + 8 * lgrp + j;
        int key = (s ^ (s >> 3)) & 7;
        f[j] = Vt[s * R + 4 * (jbr ^ key) + re];
      }
      bfu av;
      av.u[0] = pack_hi2(f[0], f[1]); av.u[1] = pack_hi2(f[2], f[3]);
      av.u[2] = pack_hi2(f[4], f[5]); av.u[3] = pack_hi2(f[6], f[7]);
      a2 = __builtin_amdgcn_mfma_f32_16x16x32_bf16(av.v, bp[k2], a2, 0, 0, 0);
    }
    uint2 w2;
    w2.x = pack_hi2(a2[0], a2[1]);
    w2.y = pack_hi2(a2[2], a2[3]);
    *(uint2*)&pb2[(size_t)hB * R + rtile + 4 * lgrp] = w2;
  }
}

// ---------------------------------------------------------------------------
// Combine: ctx[b,h,r] = sum_c e^{m_c-M} part[b,c,h,r] / sum_c e^{m_c-M} l_c
// Two-pass over mbuf to keep VGPRs low at CH=64.
// ---------------------------------------------------------------------------
__global__ __launch_bounds__(256) void k_combine(const ushort* __restrict__ part,
                                                 const float* __restrict__ mbuf,
                                                 const float* __restrict__ lbuf,
                                                 float* __restrict__ ctx) {
  const int bid = blockIdx.x;
  const int b = bid >> 5, h = bid & 31;
  const int tid = threadIdx.x;
  float M = -3.0e38f;
  for (int c = 0; c < CH; ++c)
    M = fmaxf(M, mbuf[((size_t)b * CH + c) * H + h]);
  float denom = 0.f, s0 = 0.f, s1 = 0.f;
  for (int c = 0; c < CH; ++c) {
    float w = __expf(mbuf[((size_t)b * CH + c) * H + h] - M);
    denom += w * lbuf[((size_t)b * CH + c) * H + h];
    const ushort* pp = part + (((size_t)b * CH + c) * H + h) * R;
    uint u = *(const uint*)&pp[2 * tid];
    s0 += w * bf2f((ushort)(u & 0xFFFFu));
    s1 += w * bf2f((ushort)(u >> 16));
  }
  const float inv = 1.f / denom;
  float2 o2 = {s0 * inv, s1 * inv};
  *(float2*)&ctx[((size_t)b * H + h) * R + 2 * tid] = o2;
}

// ---------------------------------------------------------------------------
// Kernel F2: out[b, h*D+d] = Wkv[h*D+d,:] . ctx[b,h,:] + bkv[h*D+d]
// ---------------------------------------------------------------------------
__global__ __launch_bounds__(256) void k_out(const float* __restrict__ ctx,
                                             const float* __restrict__ Wkv,
                                             const float* __restrict__ bkv,
                                             float* __restrict__ out) {
  int h = blockIdx.x;
  int d0 = blockIdx.y * 32;
  __shared__ float cs[B][R];  // 32 KiB
  int tid = threadIdx.x;
  for (int idx = tid * 4; idx < B * R; idx += 1024) {
    int b = idx >> 9, r = idx & 511;
    *(float4*)&cs[b][r] = *(const float4*)&ctx[(size_t)(b * H + h) * R + r];
  }
  __syncthreads();

  int dg = tid & 31;
  int bg = tid >> 5;
  int d = d0 + dg;
  int b0 = bg * 2;
  float acc0 = 0.f, acc1 = 0.f;
  const float* wrow = Wkv + ((size_t)(h * D + d)) * R;
  for (int i = 0; i < R; i += 4) {
    float4 w4 = *(const float4*)&wrow[i];
    float4 ca = *(const float4*)&cs[b0][i];
    float4 cb = *(const float4*)&cs[b0 + 1][i];
    acc0 += w4.x * ca.x + w4.y * ca.y + w4.z * ca.z + w4.w * ca.w;
    acc1 += w4.x * cb.x + w4.y * cb.y + w4.z * cb.z + w4.w * cb.w;
  }
  float bv = bkv[h * D + d];
  out[(size_t)b0 * HD + h * D + d]       = acc0 + bv;
  out[(size_t)(b0 + 1) * HD + h * D + d] = acc1 + bv;
}

// ---------------------------------------------------------------------------
extern "C" void kernel_launch(void* const* d_in, const int* in_sizes, int n_in,
                              void* d_out, int out_size, void* d_ws, size_t ws_size,
                              hipStream_t stream) {
  (void)in_sizes; (void)n_in; (void)out_size; (void)ws_size;
  const float* hsq = (const float*)d_in[0];
  const float* ckv = (const float*)d_in[1];
  const float* Wq  = (const float*)d_in[2];
  const float* bq  = (const float*)d_in[3];
  const float* Wkv = (const float*)d_in[4];
  const float* bkv = (const float*)d_in[5];
  float* out = (float*)d_out;

  float* ws   = (float*)d_ws;
  float* q    = ws;                          // 65536 f
  float* ctx  = q + 65536;                   // 262144 f
  float* mbuf = ctx + 262144;                // 32768 f
  float* lbuf = mbuf + 32768;                // 32768 f
  ushort* qhi  = (ushort*)(lbuf + 32768);    // 262144 us
  ushort* qlo  = qhi + 262144;               // 262144 us
  ushort* part = qlo + 262144;               // 16777216 us (32 MB)

  k_q<<<256, 512, 0, stream>>>(hsq, Wq, bq, q);
  k_qhat<<<dim3(32, 8), 256, 0, stream>>>(q, Wkv, qhi, qlo);
  k_fmha<<<dim3(B, CH), 512, 0, stream>>>(qhi, qlo, ckv, part, mbuf, lbuf);
  k_combine<<<B * H, 256, 0, stream>>>(part, mbuf, lbuf, ctx);
  k_out<<<dim3(32, 4), 256, 0, stream>>>(ctx, Wkv, bkv, out);
}